// Round 2
// baseline (289.890 us; speedup 1.0000x reference)
//
#include <hip/hip_runtime.h>

// Problem constants (from reference):
//   N_SLICES=24, B=16, C=512, H=W=16 (HW=256), FEAT_IN=1024, CLASSES=3
// feat_o[b,c] == max_n mean_hw(oct_maps[n,b,c,:,:])  (argmax+gather+mean == max of means)

#define NS 24
#define BDIM 16
#define CDIM 512
#define HW 256
#define BC (BDIM * CDIM)         // 8192
#define SEG_F4 (HW / 4)          // 64 float4 per segment
#define SLICE_F4 ((size_t)BC * SEG_F4)  // float4 stride between slices

// Kernel 1: one wave (64 lanes) per (b,c). Issue ALL 25 segment loads up
// front (max MLP), per-lane partial sums, then one batched butterfly
// reduction over all 25 partials at the end.
__global__ __launch_bounds__(256, 4) void reduce_feat_kernel(
    const float* __restrict__ feat_f_map,   // [B][C][HW]
    const float* __restrict__ oct,          // [NS][B][C][HW]
    float* __restrict__ feat)               // [B][1024]  (ws)
{
    const int wave = threadIdx.x >> 6;
    const int lane = threadIdx.x & 63;
    const int bc   = blockIdx.x * 4 + wave;   // 0..8191
    const int b    = bc >> 9;
    const int c    = bc & 511;

    float p[NS + 1];

    // feat_f segment
    {
        const float4* pf = reinterpret_cast<const float4*>(feat_f_map) + (size_t)bc * SEG_F4 + lane;
        float4 v = *pf;
        p[NS] = (v.x + v.y) + (v.z + v.w);
    }

    // all 24 oct segments — independent loads, compiler can keep many in flight
    const float4* po = reinterpret_cast<const float4*>(oct) + (size_t)bc * SEG_F4 + lane;
    #pragma unroll
    for (int n = 0; n < NS; ++n) {
        float4 w = po[(size_t)n * SLICE_F4];
        p[n] = (w.x + w.y) + (w.z + w.w);
    }

    // batched butterfly: 6 rounds x 25 independent shuffles per round
    #pragma unroll
    for (int off = 32; off; off >>= 1) {
        #pragma unroll
        for (int n = 0; n < NS + 1; ++n)
            p[n] += __shfl_down(p[n], off);
    }

    if (lane == 0) {
        float mx = p[0];
        #pragma unroll
        for (int n = 1; n < NS; ++n) mx = fmaxf(mx, p[n]);
        feat[b * 1024 + c]       = p[NS] * (1.0f / 256.0f);
        feat[b * 1024 + 512 + c] = mx    * (1.0f / 256.0f);
    }
}

// Kernel 2: labels[b][k] = dot(feat[b], head_w[k]) + head_b[k]
// 48 outputs; one wave per output.
__global__ __launch_bounds__(64) void head_kernel(
    const float* __restrict__ feat,     // [B][1024]
    const float* __restrict__ head_w,   // [3][1024]
    const float* __restrict__ head_b,   // [3]
    float* __restrict__ out)            // [B][3]
{
    const int j = blockIdx.x;           // 0..47
    const int b = j / 3;
    const int k = j % 3;
    const int lane = threadIdx.x;

    const float* f = feat + b * 1024;
    const float* w = head_w + k * 1024;

    float s = 0.0f;
    #pragma unroll
    for (int i = 0; i < 1024 / 64; ++i)
        s += f[lane + i * 64] * w[lane + i * 64];

    #pragma unroll
    for (int off = 32; off; off >>= 1) s += __shfl_down(s, off);

    if (lane == 0) out[b * 3 + k] = s + head_b[k];
}

extern "C" void kernel_launch(void* const* d_in, const int* in_sizes, int n_in,
                              void* d_out, int out_size, void* d_ws, size_t ws_size,
                              hipStream_t stream) {
    const float* feat_f_map = (const float*)d_in[0];   // 16*512*256
    const float* oct        = (const float*)d_in[1];   // 24*16*512*256
    const float* head_w     = (const float*)d_in[2];   // 3*1024
    const float* head_b     = (const float*)d_in[3];   // 3
    float* out  = (float*)d_out;                       // 48
    float* feat = (float*)d_ws;                        // 16*1024 floats = 64 KB scratch

    // 8192 (b,c) pairs, 4 waves (one per pair) per 256-thread block.
    reduce_feat_kernel<<<BC / 4, 256, 0, stream>>>(feat_f_map, oct, feat);
    head_kernel<<<48, 64, 0, stream>>>(feat, head_w, head_b, out);
}

// Round 3
// 284.226 us; speedup vs baseline: 1.0199x; 1.0199x over previous
//
#include <hip/hip_runtime.h>

// Problem constants (from reference):
//   N_SLICES=24, B=16, C=512, H=W=16 (HW=256), FEAT_IN=1024, CLASSES=3
// Identity: feat_o[b,c] == max_n mean_hw(oct_maps[n,b,c,:,:])
//
// Flattened: 204,800 segments of 256 contiguous floats each
//   seg s in [0, 8192)        -> feat_f_map segment s
//   seg s in [8192, 204800)   -> oct segment s-8192  (= n*8192 + bc)
// 204800 = 12800 waves * 16 segments, exactly. No guards needed.

#define NS 24
#define BC 8192                    // B*C
#define NSEG (BC * (NS + 1))       // 204800
#define SEGS_PER_WAVE 16
#define NWAVES (NSEG / SEGS_PER_WAVE)   // 12800
#define NBLOCKS (NWAVES / 4)            // 3200

// Kernel A: per-segment sums. One wave handles 16 consecutive segments
// (16 KB contiguous), 2 batches of 8. Small register footprint (~45 VGPR),
// no spills, batched butterfly reduction.
__global__ __launch_bounds__(256) void segsum_kernel(
    const float* __restrict__ feat_f_map,   // [8192][256]
    const float* __restrict__ oct,          // [196608][256]
    float* __restrict__ sums)               // [204800] (ws)
{
    const int wid  = (blockIdx.x * blockDim.x + threadIdx.x) >> 6;  // 0..12799
    const int lane = threadIdx.x & 63;
    const int s0   = wid * SEGS_PER_WAVE;

    #pragma unroll
    for (int batch = 0; batch < 2; ++batch) {
        const int s = s0 + batch * 8;       // batch of 8 segments, never crosses
                                            // the feat_f/oct boundary (8192 % 8 == 0)
        const float4* base = (s < BC)
            ? reinterpret_cast<const float4*>(feat_f_map) + (size_t)s * 64
            : reinterpret_cast<const float4*>(oct) + (size_t)(s - BC) * 64;

        float4 v[8];
        #pragma unroll
        for (int k = 0; k < 8; ++k) v[k] = base[k * 64 + lane];

        float q[8];
        #pragma unroll
        for (int k = 0; k < 8; ++k) q[k] = (v[k].x + v[k].y) + (v[k].z + v[k].w);

        // batched butterfly: 6 rounds x 8 independent shuffles
        #pragma unroll
        for (int off = 32; off; off >>= 1) {
            #pragma unroll
            for (int k = 0; k < 8; ++k) q[k] += __shfl_down(q[k], off);
        }

        if (lane == 0) {
            #pragma unroll
            for (int k = 0; k < 8; ++k) sums[s + k] = q[k];
        }
    }
}

// Kernel B: feat[b][c] = sums[bc]/256 ; feat[b][512+c] = max_n sums[8192+n*8192+bc]/256
__global__ __launch_bounds__(256) void maxcat_kernel(
    const float* __restrict__ sums,   // [204800]
    float* __restrict__ feat)         // [16][1024]
{
    const int bc = blockIdx.x * blockDim.x + threadIdx.x;   // 0..8191
    const int b  = bc >> 9;
    const int c  = bc & 511;

    float mx = sums[BC + bc];
    #pragma unroll
    for (int n = 1; n < NS; ++n) mx = fmaxf(mx, sums[BC + n * BC + bc]);

    feat[b * 1024 + c]       = sums[bc] * (1.0f / 256.0f);
    feat[b * 1024 + 512 + c] = mx       * (1.0f / 256.0f);
}

// Kernel C: labels[b][k] = dot(feat[b], head_w[k]) + head_b[k]; one wave/output.
__global__ __launch_bounds__(64) void head_kernel(
    const float* __restrict__ feat,     // [16][1024]
    const float* __restrict__ head_w,   // [3][1024]
    const float* __restrict__ head_b,   // [3]
    float* __restrict__ out)            // [16][3]
{
    const int j = blockIdx.x;           // 0..47
    const int b = j / 3;
    const int k = j % 3;
    const int lane = threadIdx.x;

    const float* f = feat + b * 1024;
    const float* w = head_w + k * 1024;

    float s = 0.0f;
    #pragma unroll
    for (int i = 0; i < 1024 / 64; ++i)
        s += f[lane + i * 64] * w[lane + i * 64];

    #pragma unroll
    for (int off = 32; off; off >>= 1) s += __shfl_down(s, off);

    if (lane == 0) out[b * 3 + k] = s + head_b[k];
}

extern "C" void kernel_launch(void* const* d_in, const int* in_sizes, int n_in,
                              void* d_out, int out_size, void* d_ws, size_t ws_size,
                              hipStream_t stream) {
    const float* feat_f_map = (const float*)d_in[0];   // 16*512*256
    const float* oct        = (const float*)d_in[1];   // 24*16*512*256
    const float* head_w     = (const float*)d_in[2];   // 3*1024
    const float* head_b     = (const float*)d_in[3];   // 3
    float* out  = (float*)d_out;                       // 48

    float* sums = (float*)d_ws;                        // 204800 floats
    float* feat = sums + NSEG;                         // 16*1024 floats

    segsum_kernel<<<NBLOCKS, 256, 0, stream>>>(feat_f_map, oct, sums);
    maxcat_kernel<<<BC / 256, 256, 0, stream>>>(sums, feat);
    head_kernel<<<48, 64, 0, stream>>>(feat, head_w, head_b, out);
}